// Round 1
// baseline (354.124 us; speedup 1.0000x reference)
//
#include <hip/hip_runtime.h>

#define N_NODES 50000
#define N_EDGES 600000
#define CH 128
#define NUM_GRAPHS 512
#define OUT_CH 64

// ---------------- CSR build (counting sort by dst) ----------------

__global__ void k_count(const int* __restrict__ dst, int* __restrict__ deg) {
    int e = blockIdx.x * 256 + threadIdx.x;
    if (e < N_EDGES) atomicAdd(&deg[dst[e]], 1);
}

// 49 blocks x 256 threads, 4 elems/thread (49*1024 >= 50000)
__global__ void k_scan1(const int* __restrict__ deg, int* __restrict__ off,
                        int* __restrict__ bsum) {
    __shared__ int sd[256];
    int tid = threadIdx.x;
    int base = blockIdx.x * 1024 + tid * 4;
    int v0 = (base + 0 < N_NODES) ? deg[base + 0] : 0;
    int v1 = (base + 1 < N_NODES) ? deg[base + 1] : 0;
    int v2 = (base + 2 < N_NODES) ? deg[base + 2] : 0;
    int v3 = (base + 3 < N_NODES) ? deg[base + 3] : 0;
    int tsum = v0 + v1 + v2 + v3;
    sd[tid] = tsum;
    __syncthreads();
    for (int d = 1; d < 256; d <<= 1) {
        int t = (tid >= d) ? sd[tid - d] : 0;
        __syncthreads();
        sd[tid] += t;
        __syncthreads();
    }
    int excl = sd[tid] - tsum;  // exclusive prefix of thread totals
    if (base + 0 < N_NODES) off[base + 0] = excl;
    if (base + 1 < N_NODES) off[base + 1] = excl + v0;
    if (base + 2 < N_NODES) off[base + 2] = excl + v0 + v1;
    if (base + 3 < N_NODES) off[base + 3] = excl + v0 + v1 + v2;
    if (tid == 255) bsum[blockIdx.x] = sd[255];
}

__global__ void k_scan2(const int* __restrict__ bsum, int* __restrict__ bsum2, int nblk) {
    __shared__ int sd[64];
    int tid = threadIdx.x;
    int v = (tid < nblk) ? bsum[tid] : 0;
    sd[tid] = v;
    __syncthreads();
    for (int d = 1; d < 64; d <<= 1) {
        int t = (tid >= d) ? sd[tid - d] : 0;
        __syncthreads();
        sd[tid] += t;
        __syncthreads();
    }
    bsum2[tid] = sd[tid] - v;
}

__global__ void k_scan3(int* __restrict__ off, int* __restrict__ cur,
                        const int* __restrict__ bsum2) {
    int base = blockIdx.x * 1024 + threadIdx.x * 4;
    int add = bsum2[blockIdx.x];
    #pragma unroll
    for (int j = 0; j < 4; ++j) {
        int i = base + j;
        if (i < N_NODES) {
            int v = off[i] + add;
            off[i] = v;
            cur[i] = v;
        }
    }
}

__global__ void k_fill(const int* __restrict__ src, const int* __restrict__ dst,
                       int* __restrict__ cur, int* __restrict__ srcs) {
    int e = blockIdx.x * 256 + threadIdx.x;
    if (e < N_EDGES) {
        int d = dst[e];
        int p = atomicAdd(&cur[d], 1);
        srcs[p] = src[e];
    }
}

__global__ void k_dinv(const int* __restrict__ deg, float* __restrict__ dinv) {
    int n = blockIdx.x * 256 + threadIdx.x;
    if (n < N_NODES) dinv[n] = rsqrtf((float)(deg[n] + 1));  // +1 self-loop
}

// ---------------- dense GEMM: out[N,128] = A[N,128] @ W[128,128] ----------------
// 64 rows/block, 256 threads; thread (rg,cg): rows rg*2+{0,1}, channels cg*4 + j*32.
__global__ __launch_bounds__(256) void k_gemm(const float* __restrict__ A,
                                              const float* __restrict__ W,
                                              float* __restrict__ out) {
    __shared__ float xs[64][68];   // +4 pad breaks row-stride bank aliasing
    __shared__ float ws[64][128];
    int tid = threadIdx.x;
    int cg = tid & 7;
    int rg = tid >> 3;
    int row0 = blockIdx.x * 64;
    float acc[2][16];
    #pragma unroll
    for (int i = 0; i < 2; ++i)
        #pragma unroll
        for (int j = 0; j < 16; ++j) acc[i][j] = 0.f;

    for (int kc = 0; kc < CH; kc += 64) {
        #pragma unroll
        for (int it = 0; it < 4; ++it) {       // x chunk: 64x64 = 1024 float4
            int idx = it * 256 + tid;
            int r = idx >> 4;
            int k4 = (idx & 15) << 2;
            float4 v = make_float4(0.f, 0.f, 0.f, 0.f);
            int gr = row0 + r;
            if (gr < N_NODES) v = *(const float4*)&A[gr * CH + kc + k4];
            *(float4*)&xs[r][k4] = v;
        }
        #pragma unroll
        for (int it = 0; it < 8; ++it) {       // W chunk: 64x128 = 2048 float4
            int idx = it * 256 + tid;
            int k = idx >> 5;
            int c4 = (idx & 31) << 2;
            *(float4*)&ws[k][c4] = *(const float4*)&W[(kc + k) * CH + c4];
        }
        __syncthreads();
        #pragma unroll 4
        for (int k = 0; k < 64; ++k) {
            float a0 = xs[rg * 2 + 0][k];
            float a1 = xs[rg * 2 + 1][k];
            #pragma unroll
            for (int j = 0; j < 4; ++j) {
                float4 w = *(float4*)&ws[k][cg * 4 + j * 32];  // conflict-free: banks cg*4..+3
                acc[0][j * 4 + 0] += a0 * w.x;
                acc[0][j * 4 + 1] += a0 * w.y;
                acc[0][j * 4 + 2] += a0 * w.z;
                acc[0][j * 4 + 3] += a0 * w.w;
                acc[1][j * 4 + 0] += a1 * w.x;
                acc[1][j * 4 + 1] += a1 * w.y;
                acc[1][j * 4 + 2] += a1 * w.z;
                acc[1][j * 4 + 3] += a1 * w.w;
            }
        }
        __syncthreads();
    }
    #pragma unroll
    for (int rr = 0; rr < 2; ++rr) {
        int gr = row0 + rg * 2 + rr;
        if (gr < N_NODES) {
            #pragma unroll
            for (int j = 0; j < 4; ++j) {
                float4 v = make_float4(acc[rr][j * 4 + 0], acc[rr][j * 4 + 1],
                                       acc[rr][j * 4 + 2], acc[rr][j * 4 + 3]);
                *(float4*)&out[gr * CH + cg * 4 + j * 32] = v;
            }
        }
    }
}

// ---------------- aggregation: out[d] = relu(dinv[d]*(sum dinv[s]h[s] + dinv[d]h[d]) + b)
// one 32-lane group per node; lane owns 4 channels (float4)
__global__ __launch_bounds__(256) void k_agg(const float* __restrict__ h,
                                             const float* __restrict__ dinv,
                                             const int* __restrict__ off,
                                             const int* __restrict__ deg,
                                             const int* __restrict__ srcs,
                                             const float* __restrict__ bias,
                                             float* __restrict__ out) {
    int node = blockIdx.x * 8 + (threadIdx.x >> 5);
    if (node >= N_NODES) return;
    int lane = threadIdx.x & 31;
    const float4* hv = (const float4*)h;
    float dn = dinv[node];
    float4 hs = hv[node * 32 + lane];
    float ax = hs.x * dn, ay = hs.y * dn, az = hs.z * dn, aw = hs.w * dn;  // self-loop
    int start = off[node];
    int cnt = deg[node];
    for (int base = 0; base < cnt; base += 32) {
        int e = base + lane;
        int s = 0;
        float ds = 0.f;
        if (e < cnt) {
            s = srcs[start + e];
            ds = dinv[s];
        }
        int m = min(32, cnt - base);
        for (int j = 0; j < m; ++j) {
            int ss = __shfl(s, j, 32);
            float dss = __shfl(ds, j, 32);
            float4 v = hv[ss * 32 + lane];
            ax += v.x * dss;
            ay += v.y * dss;
            az += v.z * dss;
            aw += v.w * dss;
        }
    }
    float4 b = *(const float4*)&bias[lane * 4];
    ax = fmaxf(ax * dn + b.x, 0.f);
    ay = fmaxf(ay * dn + b.y, 0.f);
    az = fmaxf(az * dn + b.z, 0.f);
    aw = fmaxf(aw * dn + b.w, 0.f);
    *(float4*)&out[node * CH + lane * 4] = make_float4(ax, ay, az, aw);
}

// ---------------- mean-pool per graph (batch is sorted) ----------------
__global__ void k_pool(const float* __restrict__ h, const int* __restrict__ batch,
                       float* __restrict__ pooled) {
    __shared__ int sb[2];
    int g = blockIdx.x;
    if (threadIdx.x < 2) {
        int target = g + (int)threadIdx.x;
        int lo = 0, hi = N_NODES;
        while (lo < hi) {
            int mid = (lo + hi) >> 1;
            if (batch[mid] < target) lo = mid + 1; else hi = mid;
        }
        sb[threadIdx.x] = lo;
    }
    __syncthreads();
    int lo = sb[0], hi = sb[1];
    int c = threadIdx.x;  // 128 threads
    float acc = 0.f;
    for (int i = lo; i < hi; ++i) acc += h[i * CH + c];
    float cnt = (float)((hi - lo) > 0 ? (hi - lo) : 1);
    pooled[g * CH + c] = acc / cnt;
}

// ---------------- final linear: out[512,64] = pooled @ Wlin + blin ----------------
__global__ void k_linear(const float* __restrict__ pooled, const float* __restrict__ Wl,
                         const float* __restrict__ bl, float* __restrict__ out) {
    __shared__ float xr[CH];
    int g = blockIdx.x;
    int c = threadIdx.x;  // 64 threads
    xr[c] = pooled[g * CH + c];
    xr[c + 64] = pooled[g * CH + c + 64];
    __syncthreads();
    float acc = bl[c];
    #pragma unroll 8
    for (int k = 0; k < CH; ++k) acc += xr[k] * Wl[k * OUT_CH + c];
    out[g * OUT_CH + c] = acc;
}

extern "C" void kernel_launch(void* const* d_in, const int* in_sizes, int n_in,
                              void* d_out, int out_size, void* d_ws, size_t ws_size,
                              hipStream_t stream) {
    const float* x    = (const float*)d_in[0];
    const float* W1   = (const float*)d_in[1];
    const float* b1   = (const float*)d_in[2];
    const float* W2   = (const float*)d_in[3];
    const float* b2   = (const float*)d_in[4];
    const float* Wlin = (const float*)d_in[5];
    const float* blin = (const float*)d_in[6];
    const int* ei     = (const int*)d_in[7];
    const int* batch  = (const int*)d_in[8];
    const int* esrc = ei;
    const int* edst = ei + N_EDGES;
    float* out = (float*)d_out;

    char* w = (char*)d_ws;
    size_t o = 0;
    float* h1     = (float*)(w + o); o += (size_t)N_NODES * CH * 4;   // 25.6 MB
    float* h2     = (float*)(w + o); o += (size_t)N_NODES * CH * 4;   // 25.6 MB
    float* pooled = (float*)(w + o); o += (size_t)NUM_GRAPHS * CH * 4;
    float* dinv   = (float*)(w + o); o += 200704;
    int* deg      = (int*)(w + o);   o += 200704;
    int* off      = (int*)(w + o);   o += 200704;
    int* cur      = (int*)(w + o);   o += 200704;
    int* srcs     = (int*)(w + o);   o += (size_t)N_EDGES * 4;
    int* bsum     = (int*)(w + o);   o += 256;
    int* bsum2    = (int*)(w + o);   o += 256;
    (void)ws_size; (void)in_sizes; (void)n_in; (void)out_size;

    hipMemsetAsync(deg, 0, N_NODES * sizeof(int), stream);

    dim3 b256(256);
    dim3 gE((N_EDGES + 255) / 256);
    k_count<<<gE, b256, 0, stream>>>(edst, deg);
    k_scan1<<<dim3(49), b256, 0, stream>>>(deg, off, bsum);
    k_scan2<<<dim3(1), dim3(64), 0, stream>>>(bsum, bsum2, 49);
    k_scan3<<<dim3(49), b256, 0, stream>>>(off, cur, bsum2);
    k_fill<<<gE, b256, 0, stream>>>(esrc, edst, cur, srcs);
    k_dinv<<<dim3((N_NODES + 255) / 256), b256, 0, stream>>>(deg, dinv);

    dim3 gG((N_NODES + 63) / 64);
    dim3 gA(N_NODES / 8);  // 6250, exact
    k_gemm<<<gG, b256, 0, stream>>>(x, W1, h1);
    k_agg<<<gA, b256, 0, stream>>>(h1, dinv, off, deg, srcs, b1, h2);
    k_gemm<<<gG, b256, 0, stream>>>(h2, W2, h1);
    k_agg<<<gA, b256, 0, stream>>>(h1, dinv, off, deg, srcs, b2, h2);
    k_pool<<<dim3(NUM_GRAPHS), dim3(128), 0, stream>>>(h2, batch, pooled);
    k_linear<<<dim3(NUM_GRAPHS), dim3(OUT_CH), 0, stream>>>(pooled, Wlin, blin, out);
}

// Round 2
// 340.234 us; speedup vs baseline: 1.0408x; 1.0408x over previous
//
#include <hip/hip_runtime.h>

#define N_NODES 50000
#define N_EDGES 600000
#define CH 128
#define NUM_GRAPHS 512
#define OUT_CH 64

// ---------------- CSR build (counting sort by dst) ----------------

__global__ void k_count(const int* __restrict__ dst, int* __restrict__ deg) {
    int e = blockIdx.x * 256 + threadIdx.x;
    if (e < N_EDGES) atomicAdd(&deg[dst[e]], 1);
}

// 49 blocks x 256 threads, 4 elems/thread (49*1024 >= 50000)
__global__ void k_scan1(const int* __restrict__ deg, int* __restrict__ off,
                        int* __restrict__ bsum) {
    __shared__ int sd[256];
    int tid = threadIdx.x;
    int base = blockIdx.x * 1024 + tid * 4;
    int v0 = (base + 0 < N_NODES) ? deg[base + 0] : 0;
    int v1 = (base + 1 < N_NODES) ? deg[base + 1] : 0;
    int v2 = (base + 2 < N_NODES) ? deg[base + 2] : 0;
    int v3 = (base + 3 < N_NODES) ? deg[base + 3] : 0;
    int tsum = v0 + v1 + v2 + v3;
    sd[tid] = tsum;
    __syncthreads();
    for (int d = 1; d < 256; d <<= 1) {
        int t = (tid >= d) ? sd[tid - d] : 0;
        __syncthreads();
        sd[tid] += t;
        __syncthreads();
    }
    int excl = sd[tid] - tsum;
    if (base + 0 < N_NODES) off[base + 0] = excl;
    if (base + 1 < N_NODES) off[base + 1] = excl + v0;
    if (base + 2 < N_NODES) off[base + 2] = excl + v0 + v1;
    if (base + 3 < N_NODES) off[base + 3] = excl + v0 + v1 + v2;
    if (tid == 255) bsum[blockIdx.x] = sd[255];
}

__global__ void k_scan2(const int* __restrict__ bsum, int* __restrict__ bsum2, int nblk) {
    __shared__ int sd[64];
    int tid = threadIdx.x;
    int v = (tid < nblk) ? bsum[tid] : 0;
    sd[tid] = v;
    __syncthreads();
    for (int d = 1; d < 64; d <<= 1) {
        int t = (tid >= d) ? sd[tid - d] : 0;
        __syncthreads();
        sd[tid] += t;
        __syncthreads();
    }
    bsum2[tid] = sd[tid] - v;
}

// also computes dinv (fused, saves a launch)
__global__ void k_scan3(int* __restrict__ off, int* __restrict__ cur,
                        const int* __restrict__ bsum2, const int* __restrict__ deg,
                        float* __restrict__ dinv) {
    int base = blockIdx.x * 1024 + threadIdx.x * 4;
    int add = bsum2[blockIdx.x];
    #pragma unroll
    for (int j = 0; j < 4; ++j) {
        int i = base + j;
        if (i < N_NODES) {
            int v = off[i] + add;
            off[i] = v;
            cur[i] = v;
            dinv[i] = rsqrtf((float)(deg[i] + 1));
        }
    }
}

__global__ void k_fill(const int* __restrict__ src, const int* __restrict__ dst,
                       int* __restrict__ cur, int* __restrict__ srcs) {
    int e = blockIdx.x * 256 + threadIdx.x;
    if (e < N_EDGES) {
        int d = dst[e];
        int p = atomicAdd(&cur[d], 1);
        srcs[p] = src[e];
    }
}

// ---------------- dense GEMM: out[N,128] = A[N,128] @ W[128,128] ----------------
__global__ __launch_bounds__(256) void k_gemm(const float* __restrict__ A,
                                              const float* __restrict__ W,
                                              float* __restrict__ out) {
    __shared__ float xs[64][68];
    __shared__ float ws[64][128];
    int tid = threadIdx.x;
    int cg = tid & 7;
    int rg = tid >> 3;
    int row0 = blockIdx.x * 64;
    float acc[2][16];
    #pragma unroll
    for (int i = 0; i < 2; ++i)
        #pragma unroll
        for (int j = 0; j < 16; ++j) acc[i][j] = 0.f;

    for (int kc = 0; kc < CH; kc += 64) {
        #pragma unroll
        for (int it = 0; it < 4; ++it) {
            int idx = it * 256 + tid;
            int r = idx >> 4;
            int k4 = (idx & 15) << 2;
            float4 v = make_float4(0.f, 0.f, 0.f, 0.f);
            int gr = row0 + r;
            if (gr < N_NODES) v = *(const float4*)&A[gr * CH + kc + k4];
            *(float4*)&xs[r][k4] = v;
        }
        #pragma unroll
        for (int it = 0; it < 8; ++it) {
            int idx = it * 256 + tid;
            int k = idx >> 5;
            int c4 = (idx & 31) << 2;
            *(float4*)&ws[k][c4] = *(const float4*)&W[(kc + k) * CH + c4];
        }
        __syncthreads();
        #pragma unroll 4
        for (int k = 0; k < 64; ++k) {
            float a0 = xs[rg * 2 + 0][k];
            float a1 = xs[rg * 2 + 1][k];
            #pragma unroll
            for (int j = 0; j < 4; ++j) {
                float4 w = *(float4*)&ws[k][cg * 4 + j * 32];
                acc[0][j * 4 + 0] += a0 * w.x;
                acc[0][j * 4 + 1] += a0 * w.y;
                acc[0][j * 4 + 2] += a0 * w.z;
                acc[0][j * 4 + 3] += a0 * w.w;
                acc[1][j * 4 + 0] += a1 * w.x;
                acc[1][j * 4 + 1] += a1 * w.y;
                acc[1][j * 4 + 2] += a1 * w.z;
                acc[1][j * 4 + 3] += a1 * w.w;
            }
        }
        __syncthreads();
    }
    #pragma unroll
    for (int rr = 0; rr < 2; ++rr) {
        int gr = row0 + rg * 2 + rr;
        if (gr < N_NODES) {
            #pragma unroll
            for (int j = 0; j < 4; ++j) {
                float4 v = make_float4(acc[rr][j * 4 + 0], acc[rr][j * 4 + 1],
                                       acc[rr][j * 4 + 2], acc[rr][j * 4 + 3]);
                *(float4*)&out[gr * CH + cg * 4 + j * 32] = v;
            }
        }
    }
}

// ---------------- aggregation v2: one wave64 per node, 2 edges/step, 4x unrolled
// out[d] = relu(dinv[d]*(sum_e dinv[s]h[s] + dinv[d]h[d]) + b)
// lanes 0-31 = half A (edge j), lanes 32-63 = half B (edge j+1); lane owns 4 ch.
__global__ __launch_bounds__(256) void k_agg(const float* __restrict__ h,
                                             const float* __restrict__ dinv,
                                             const int* __restrict__ off,
                                             const int* __restrict__ deg,
                                             const int* __restrict__ srcs,
                                             const float* __restrict__ bias,
                                             float* __restrict__ out) {
    int node = blockIdx.x * 4 + (threadIdx.x >> 6);
    int lane = threadIdx.x & 63;
    int half = lane >> 5;
    int cl = lane & 31;
    const float4* hv = (const float4*)h;

    float dn = dinv[node];
    float4 hs = hv[node * 32 + cl];
    float dself = half ? 0.f : dn;  // only half A counts the self-loop
    float ax = hs.x * dself, ay = hs.y * dself, az = hs.z * dself, aw = hs.w * dself;

    int start = off[node];
    int cnt = deg[node];
    for (int base = 0; base < cnt; base += 64) {
        int e = base + lane;
        int s = 0;
        float ds = 0.f;
        if (e < cnt) {
            s = srcs[start + e];
            ds = dinv[s];
        }
        int m2 = min(64, cnt - base);
        int j = 0;
        // 8 edges (4 independent 1KB loads) per iteration
        for (; j + 8 <= m2; j += 8) {
            int s0 = __shfl(s, j + 0 + half);
            int s1 = __shfl(s, j + 2 + half);
            int s2 = __shfl(s, j + 4 + half);
            int s3 = __shfl(s, j + 6 + half);
            float d0 = __shfl(ds, j + 0 + half);
            float d1 = __shfl(ds, j + 2 + half);
            float d2 = __shfl(ds, j + 4 + half);
            float d3 = __shfl(ds, j + 6 + half);
            float4 v0 = hv[s0 * 32 + cl];
            float4 v1 = hv[s1 * 32 + cl];
            float4 v2 = hv[s2 * 32 + cl];
            float4 v3 = hv[s3 * 32 + cl];
            ax += v0.x * d0; ay += v0.y * d0; az += v0.z * d0; aw += v0.w * d0;
            ax += v1.x * d1; ay += v1.y * d1; az += v1.z * d1; aw += v1.w * d1;
            ax += v2.x * d2; ay += v2.y * d2; az += v2.z * d2; aw += v2.w * d2;
            ax += v3.x * d3; ay += v3.y * d3; az += v3.z * d3; aw += v3.w * d3;
        }
        // remainder, 2 edges per step (out-of-range lanes have ds==0)
        for (; j < m2; j += 2) {
            int ss = __shfl(s, j + half);
            float dss = __shfl(ds, j + half);
            float4 v = hv[ss * 32 + cl];
            ax += v.x * dss; ay += v.y * dss; az += v.z * dss; aw += v.w * dss;
        }
    }
    // combine the two halves
    ax += __shfl_xor(ax, 32);
    ay += __shfl_xor(ay, 32);
    az += __shfl_xor(az, 32);
    aw += __shfl_xor(aw, 32);
    if (half == 0) {
        float4 b = *(const float4*)&bias[cl * 4];
        ax = fmaxf(ax * dn + b.x, 0.f);
        ay = fmaxf(ay * dn + b.y, 0.f);
        az = fmaxf(az * dn + b.z, 0.f);
        aw = fmaxf(aw * dn + b.w, 0.f);
        *(float4*)&out[node * CH + cl * 4] = make_float4(ax, ay, az, aw);
    }
}

// ---------------- fused mean-pool + linear (batch is sorted) ----------------
__global__ void k_pool_linear(const float* __restrict__ h, const int* __restrict__ batch,
                              const float* __restrict__ Wl, const float* __restrict__ bl,
                              float* __restrict__ out) {
    __shared__ int sb[2];
    __shared__ float xr[CH];
    int g = blockIdx.x;
    if (threadIdx.x < 2) {
        int target = g + (int)threadIdx.x;
        int lo = 0, hi = N_NODES;
        while (lo < hi) {
            int mid = (lo + hi) >> 1;
            if (batch[mid] < target) lo = mid + 1; else hi = mid;
        }
        sb[threadIdx.x] = lo;
    }
    __syncthreads();
    int lo = sb[0], hi = sb[1];
    int c = threadIdx.x;  // 128 threads
    float acc = 0.f;
    for (int i = lo; i < hi; ++i) acc += h[i * CH + c];
    float cnt = (float)((hi - lo) > 0 ? (hi - lo) : 1);
    xr[c] = acc / cnt;
    __syncthreads();
    if (c < OUT_CH) {
        float o = bl[c];
        #pragma unroll 8
        for (int k = 0; k < CH; ++k) o += xr[k] * Wl[k * OUT_CH + c];
        out[g * OUT_CH + c] = o;
    }
}

extern "C" void kernel_launch(void* const* d_in, const int* in_sizes, int n_in,
                              void* d_out, int out_size, void* d_ws, size_t ws_size,
                              hipStream_t stream) {
    const float* x    = (const float*)d_in[0];
    const float* W1   = (const float*)d_in[1];
    const float* b1   = (const float*)d_in[2];
    const float* W2   = (const float*)d_in[3];
    const float* b2   = (const float*)d_in[4];
    const float* Wlin = (const float*)d_in[5];
    const float* blin = (const float*)d_in[6];
    const int* ei     = (const int*)d_in[7];
    const int* batch  = (const int*)d_in[8];
    const int* esrc = ei;
    const int* edst = ei + N_EDGES;
    float* out = (float*)d_out;

    char* w = (char*)d_ws;
    size_t o = 0;
    float* h1     = (float*)(w + o); o += (size_t)N_NODES * CH * 4;
    float* h2     = (float*)(w + o); o += (size_t)N_NODES * CH * 4;
    float* dinv   = (float*)(w + o); o += 200704;
    int* deg      = (int*)(w + o);   o += 200704;
    int* off      = (int*)(w + o);   o += 200704;
    int* cur      = (int*)(w + o);   o += 200704;
    int* srcs     = (int*)(w + o);   o += (size_t)N_EDGES * 4;
    int* bsum     = (int*)(w + o);   o += 256;
    int* bsum2    = (int*)(w + o);   o += 256;
    (void)ws_size; (void)in_sizes; (void)n_in; (void)out_size;

    hipMemsetAsync(deg, 0, N_NODES * sizeof(int), stream);

    dim3 b256(256);
    dim3 gE((N_EDGES + 255) / 256);
    k_count<<<gE, b256, 0, stream>>>(edst, deg);
    k_scan1<<<dim3(49), b256, 0, stream>>>(deg, off, bsum);
    k_scan2<<<dim3(1), dim3(64), 0, stream>>>(bsum, bsum2, 49);
    k_scan3<<<dim3(49), b256, 0, stream>>>(off, cur, bsum2, deg, dinv);
    k_fill<<<gE, b256, 0, stream>>>(esrc, edst, cur, srcs);

    dim3 gG((N_NODES + 63) / 64);
    dim3 gA(N_NODES / 4);  // 12500, one wave64 per node
    k_gemm<<<gG, b256, 0, stream>>>(x, W1, h1);
    k_agg<<<gA, b256, 0, stream>>>(h1, dinv, off, deg, srcs, b1, h2);
    k_gemm<<<gG, b256, 0, stream>>>(h2, W2, h1);
    k_agg<<<gA, b256, 0, stream>>>(h1, dinv, off, deg, srcs, b2, h2);
    k_pool_linear<<<dim3(NUM_GRAPHS), dim3(128), 0, stream>>>(h2, batch, Wlin, blin, out);
}